// Round 10
// baseline (279.488 us; speedup 1.0000x reference)
//
#include <hip/hip_runtime.h>
#include <hip/hip_fp16.h>
#include <cstddef>

// Problem constants
// B=8, DIM=256, NH=8, H=W=56, G=4, CG=64, GH=2, HC=32, Hk=Wk=8, ns=64

typedef short bf16x8 __attribute__((ext_vector_type(8)));
typedef float f32x4 __attribute__((ext_vector_type(4)));

static __device__ __forceinline__ ushort f2bf(float f) {
  union { float f; unsigned u; } v; v.f = f;
  unsigned r = v.u + 0x7fffu + ((v.u >> 16) & 1u);   // RNE
  return (ushort)(r >> 16);
}
static __device__ __forceinline__ float bf2f(ushort u) {
  union { unsigned u; float f; } v; v.u = ((unsigned)u) << 16;
  return v.f;
}
static __device__ __forceinline__ __half2 h2max(__half2 a, __half2 b) {
  return __halves2half2(__hmax(__low2half(a), __low2half(b)),
                        __hmax(__high2half(a), __high2half(b)));
}

// ws float offsets
#define OFF_FEATB 0u          // feat bf16 [b*3136+m][256c] (later reused as attnpk)
#define OFF_QPK   3211264u    // q bf16 [b*3136+m][256c]
#define OFF_Q     6422528u    // q fp32 [b][c][m]; ALSO aliased as xb bf16 (earlier)
#define OFF_POS   12845056u   // 4096
#define OFF_XS    12849152u   // 131072 (offset-conv scratch)
#define OFF_KPK   12980224u   // K bf16 pack [b][h][c8=4][n=64][8]
#define OFF_VPK   13045760u   // V bf16 pack [b][h][n8=8][c=32][8]
#define OFF_PWP   13111296u   // pw pack 49152 bf16 = 24576 fl
#define OFF_WQP   13135872u   // 65536 bf16 = 32768 fl
#define OFF_WOP   13168640u   // 32768 fl
#define OFF_WKP   13201408u   // 32768 fl
#define OFF_WVP   13234176u   // 32768 fl -> end 13266944 fl (53.1 MB)

// ---------------------------------------------------------------------------
// Kernel X: convert x fp32 -> bf16 (same layout).  4816896 elements.
__global__ __launch_bounds__(256) void k_xcvt(
    const float* __restrict__ x, ushort* __restrict__ xb) {
  const size_t i0 = ((size_t)blockIdx.x * 256 + threadIdx.x) * 8;
  float4 v0 = *(const float4*)(x + i0);
  float4 v1 = *(const float4*)(x + i0 + 4);
  bf16x8 o;
  o[0] = (short)f2bf(v0.x); o[1] = (short)f2bf(v0.y);
  o[2] = (short)f2bf(v0.z); o[3] = (short)f2bf(v0.w);
  o[4] = (short)f2bf(v1.x); o[5] = (short)f2bf(v1.y);
  o[6] = (short)f2bf(v1.z); o[7] = (short)f2bf(v1.w);
  *(bf16x8*)(xb + i0) = o;
}

// ---------------------------------------------------------------------------
// Kernel P: pack weights to bf16 MFMA B-frag layout [k8][o][8].
__global__ __launch_bounds__(256) void k_pack(
    const float* __restrict__ pw, const float* __restrict__ wq,
    const float* __restrict__ wk, const float* __restrict__ wv,
    const float* __restrict__ wo, ushort* __restrict__ pwp,
    ushort* __restrict__ wqp, ushort* __restrict__ wkp,
    ushort* __restrict__ wvp, ushort* __restrict__ wop) {
  const int o = blockIdx.x, t = threadIdx.x, m = blockIdx.y;
  if (m == 0) {
    if (t < 192) pwp[((t >> 3) * 256 + o) * 8 + (t & 7)] = f2bf(pw[o * 192 + t]);
  } else {
    const float* in = (m == 1) ? wq : (m == 2) ? wk : (m == 3) ? wv : wo;
    ushort* out = (m == 1) ? wqp : (m == 2) ? wkp : (m == 3) ? wvp : wop;
    out[((t >> 3) * 256 + o) * 8 + (t & 7)] = f2bf(in[o * 256 + t]);
  }
}

// ---------------------------------------------------------------------------
// Kernel A: patch conv (im2col MFMA, K=192) + bias + channel-LN -> bf16 [m][c]
// Block = 4 waves x 32 rows = 128 rows; B slices (16KB) LDS double-buffered.
__global__ __launch_bounds__(256) void k_patch_mfma(
    const ushort* __restrict__ xb, const ushort* __restrict__ pwp,
    const float* __restrict__ pb, const float* __restrict__ g1,
    const float* __restrict__ b1, ushort* __restrict__ featb) {
  __shared__ ushort Bs[2][8192];
  const int t = threadIdx.x;
  const int lane = t & 63, w = t >> 6;
  const int lr = lane & 15, kg = lane >> 4;
  const int m_base = blockIdx.x * 128 + w * 32;

  size_t abase[2];
#pragma unroll
  for (int mr = 0; mr < 2; mr++) {
    int mA = m_base + mr * 16 + lr;
    int bA = mA / 3136;
    int posA = mA - bA * 3136;
    int ohA = posA / 56;
    int owA = posA - ohA * 56;
    abase[mr] = (((size_t)bA * 3) * 448 + ohA * 8) * 448 + owA * 8;
  }

  f32x4 acc[2][16];
#pragma unroll
  for (int f = 0; f < 16; f++) {
    float bv = pb[f * 16 + lr];
    acc[0][f] = (f32x4){bv, bv, bv, bv};
    acc[1][f] = (f32x4){bv, bv, bv, bv};
  }

  bf16x8 st[4];
#pragma unroll
  for (int i = 0; i < 4; i++)
    st[i] = *(const bf16x8*)(pwp + i * 2048 + t * 8);
#pragma unroll
  for (int i = 0; i < 4; i++)
    *(bf16x8*)(&Bs[0][i * 2048 + t * 8]) = st[i];
  __syncthreads();
  int p = 0;
  for (int ks = 0; ks < 6; ks++) {
    if (ks < 5) {
#pragma unroll
      for (int i = 0; i < 4; i++)
        st[i] = *(const bf16x8*)(pwp + (ks + 1) * 8192 + i * 2048 + t * 8);
    }
    const int k8 = ks * 4 + kg;
    const int ci = k8 >> 3, ii = k8 & 7;
    bf16x8 a0 = *(const bf16x8*)(xb + abase[0] + (size_t)ci * 200704 + ii * 448);
    bf16x8 a1 = *(const bf16x8*)(xb + abase[1] + (size_t)ci * 200704 + ii * 448);
    const ushort* bsl = &Bs[p][kg * 2048];
#pragma unroll
    for (int f = 0; f < 16; f++) {
      bf16x8 bfr = *(const bf16x8*)(bsl + (f * 16 + lr) * 8);
      acc[0][f] = __builtin_amdgcn_mfma_f32_16x16x32_bf16(a0, bfr, acc[0][f], 0, 0, 0);
      acc[1][f] = __builtin_amdgcn_mfma_f32_16x16x32_bf16(a1, bfr, acc[1][f], 0, 0, 0);
    }
    __syncthreads();
    if (ks < 5) {
#pragma unroll
      for (int i = 0; i < 4; i++)
        *(bf16x8*)(&Bs[p ^ 1][i * 2048 + t * 8]) = st[i];
      __syncthreads();
      p ^= 1;
    }
  }

#pragma unroll
  for (int mr = 0; mr < 2; mr++) {
    float mean[4], rstd[4];
#pragma unroll
    for (int j = 0; j < 4; j++) {
      float s1 = 0.f, s2 = 0.f;
#pragma unroll
      for (int f = 0; f < 16; f++) { float v = acc[mr][f][j]; s1 += v; s2 += v * v; }
#pragma unroll
      for (int off = 8; off >= 1; off >>= 1) {
        s1 += __shfl_xor(s1, off);
        s2 += __shfl_xor(s2, off);
      }
      float mn = s1 * (1.f / 256.f);
      float var = s2 * (1.f / 256.f) - mn * mn;
      mean[j] = mn; rstd[j] = rsqrtf(var + 1e-5f);
    }
#pragma unroll
    for (int f = 0; f < 16; f++) {
      const int c = f * 16 + lr;
      const float gg = g1[c], bb = b1[c];
#pragma unroll
      for (int j = 0; j < 4; j++) {
        const int mo = m_base + mr * 16 + kg * 4 + j;
        float v = (acc[mr][f][j] - mean[j]) * rstd[j] * gg + bb;
        featb[(size_t)mo * 256 + c] = f2bf(v);
      }
    }
  }
}

// ---------------------------------------------------------------------------
// Kernel B: MFMA GEMM, 128 rows/block (4 waves x 32), B staged in LDS.
__global__ __launch_bounds__(256) void k_gemm_mfma(
    const ushort* __restrict__ apk, const ushort* __restrict__ wp,
    const float* __restrict__ bias, float* __restrict__ out,
    ushort* __restrict__ opk) {
  __shared__ float smem[16448];           // 65792 B: Bs (32KB) / sA 64x257 f32
  ushort* Bs = (ushort*)smem;
  float* sA = smem;
  const int t = threadIdx.x;
  const int lane = t & 63, w = t >> 6;
  const int lr = lane & 15, kg = lane >> 4;
  const int m_base = blockIdx.x * 128 + w * 32;

  f32x4 acc[2][16];
#pragma unroll
  for (int f = 0; f < 16; f++) {
    float bv = bias[f * 16 + lr];
    acc[0][f] = (f32x4){bv, bv, bv, bv};
    acc[1][f] = (f32x4){bv, bv, bv, bv};
  }
  const ushort* a0p = apk + (size_t)(m_base + lr) * 256;
  const ushort* a1p = a0p + 16 * 256;

  bf16x8 st[4];
#pragma unroll
  for (int i = 0; i < 4; i++) st[i] = *(const bf16x8*)(wp + i * 2048 + t * 8);
#pragma unroll
  for (int i = 0; i < 4; i++) *(bf16x8*)(Bs + i * 2048 + t * 8) = st[i];
  __syncthreads();
  int p = 0;
  for (int ks = 0; ks < 8; ks++) {
    if (ks < 7) {
#pragma unroll
      for (int i = 0; i < 4; i++)
        st[i] = *(const bf16x8*)(wp + (ks + 1) * 8192 + i * 2048 + t * 8);
    }
    bf16x8 a0 = *(const bf16x8*)(a0p + ks * 32 + kg * 8);
    bf16x8 a1 = *(const bf16x8*)(a1p + ks * 32 + kg * 8);
    const ushort* bsl = Bs + p * 8192 + kg * 2048;
#pragma unroll
    for (int f = 0; f < 16; f++) {
      bf16x8 bfr = *(const bf16x8*)(bsl + (f * 16 + lr) * 8);
      acc[0][f] = __builtin_amdgcn_mfma_f32_16x16x32_bf16(a0, bfr, acc[0][f], 0, 0, 0);
      acc[1][f] = __builtin_amdgcn_mfma_f32_16x16x32_bf16(a1, bfr, acc[1][f], 0, 0, 0);
    }
    __syncthreads();
    if (ks < 7) {
#pragma unroll
      for (int i = 0; i < 4; i++)
        *(bf16x8*)(Bs + (p ^ 1) * 8192 + i * 2048 + t * 8) = st[i];
      __syncthreads();
      p ^= 1;
    }
  }
  __syncthreads();                         // reclaim smem for epilogue

#pragma unroll
  for (int h = 0; h < 2; h++) {
    if ((w >> 1) == h) {
      const int loc0 = (w & 1) * 32;
#pragma unroll
      for (int mr = 0; mr < 2; mr++)
#pragma unroll
        for (int f = 0; f < 16; f++)
#pragma unroll
          for (int j = 0; j < 4; j++)
            sA[(loc0 + mr * 16 + kg * 4 + j) * 257 + f * 16 + lr] = acc[mr][f][j];
    }
    __syncthreads();
    const int R0 = blockIdx.x * 128 + h * 64;
    const int bh = R0 / 3136;
    const int pos0 = R0 % 3136;            // multiple of 64
    {
      const int c = t;
      float* op = out + ((size_t)bh * 256 + c) * 3136 + pos0;
#pragma unroll
      for (int i4 = 0; i4 < 16; i4++) {
        float4 v;
        v.x = sA[(i4 * 4 + 0) * 257 + c];
        v.y = sA[(i4 * 4 + 1) * 257 + c];
        v.z = sA[(i4 * 4 + 2) * 257 + c];
        v.w = sA[(i4 * 4 + 3) * 257 + c];
        *(float4*)(op + i4 * 4) = v;
      }
    }
    if (opk) {
      const int mm = t & 63, cs = t >> 6;
      const int c0 = cs * 64;
#pragma unroll
      for (int jj = 0; jj < 8; jj++) {
        bf16x8 v8;
#pragma unroll
        for (int e = 0; e < 8; e++)
          v8[e] = (short)f2bf(sA[mm * 257 + c0 + jj * 8 + e]);
        *(bf16x8*)(opk + (size_t)(R0 + mm) * 256 + c0 + jj * 8) = v8;
      }
    }
    __syncthreads();
  }
}

// ---------------------------------------------------------------------------
// Kernel C1: offset depthwise conv (28x28, stride 8, pad 14).
__global__ __launch_bounds__(128) void k_offset_conv(
    const float* __restrict__ q, const float* __restrict__ dww,
    float* __restrict__ convo) {
  const int bg = blockIdx.y;
  const int wv = threadIdx.x >> 6;
  const int lane = threadIdx.x & 63;
  const int ch = blockIdx.x * 2 + wv;
  const int b = bg >> 2, g = bg & 3;

  __shared__ float pl[2][7072];
  float* P = pl[wv];
  for (int idx = lane; idx < 7072; idx += 64) P[idx] = 0.f;

  const float* qb = q + ((size_t)b * 256 + g * 64 + ch) * 3136;
  if (lane < 56) {
    for (int r = 0; r < 56; r++) {
      int hr = r + 14;
      P[hr * 84 + (lane + 14) + (hr >> 3)] = qb[r * 56 + lane];
    }
  }
  const int oh = lane >> 3, ow = lane & 7;
  const int chs = __builtin_amdgcn_readfirstlane(ch);
  const float* wr = dww + (size_t)chs * 784;
  float acc = 0.f;
  const int r0 = oh * 8, c0 = ow * 8;
  for (int i = 0; i < 28; i++) {
    int hr = r0 + i;
    const float* prow = P + hr * 84 + c0 + (hr >> 3);
    const float* wrr = wr + i * 28;
#pragma unroll
    for (int j = 0; j < 28; j++)
      acc = fmaf(prow[j], wrr[j], acc);
  }
  convo[bg * 4096 + lane * 64 + ch] = acc;
}

// ---------------------------------------------------------------------------
// Kernel C2: LN(64) + GELU + pointwise(2x64) + tanh + reference points.
__global__ __launch_bounds__(256) void k_offset_post(
    const float* __restrict__ convo, const float* __restrict__ dwb,
    const float* __restrict__ lng, const float* __restrict__ lnb,
    const float* __restrict__ pww, float* __restrict__ pos_ws,
    float* __restrict__ out_pos, float* __restrict__ out_ref) {
  const int bg = blockIdx.y;
  const int wv = threadIdx.x >> 6;
  const int lane = threadIdx.x & 63;
  const int idx = blockIdx.x * 4 + wv;
  const int oh = idx >> 3, ow = idx & 7;

  float acc = convo[bg * 4096 + idx * 64 + lane] + dwb[lane];

  float s1 = acc, s2 = acc * acc;
#pragma unroll
  for (int off = 32; off >= 1; off >>= 1) {
    s1 += __shfl_xor(s1, off);
    s2 += __shfl_xor(s2, off);
  }
  float m = s1 * (1.f / 64.f);
  float var = s2 * (1.f / 64.f) - m * m;
  float val = (acc - m) * rsqrtf(var + 1e-5f) * lng[lane] + lnb[lane];
  val = 0.5f * val * (1.f + erff(val * 0.70710678118654752f));
  float p0 = pww[lane] * val, p1 = pww[64 + lane] * val;
#pragma unroll
  for (int off = 32; off >= 1; off >>= 1) {
    p0 += __shfl_xor(p0, off);
    p1 += __shfl_xor(p1, off);
  }
  if (lane == 0) {
    float offy = tanhf(p0) * (2.0f / 7.0f);
    float offx = tanhf(p1) * (2.0f / 7.0f);
    float ry = (0.5f + oh) * (2.0f / 7.0f) - 1.0f;
    float rx = (0.5f + ow) * (2.0f / 7.0f) - 1.0f;
    float py = offy + ry, px = offx + rx;
    int o = bg * 128 + idx * 2;
    pos_ws[o] = py;  pos_ws[o + 1] = px;
    out_pos[o] = py; out_pos[o + 1] = px;
    out_ref[o] = ry; out_ref[o + 1] = rx;
  }
}

// ---------------------------------------------------------------------------
// Kernel DE: fused sampling + k,v MFMA projections. One block per batch b.
__global__ __launch_bounds__(512) void k_sample_kv(
    const ushort* __restrict__ featb, const float* __restrict__ pos_ws,
    const ushort* __restrict__ wkp, const float* __restrict__ bk,
    const ushort* __restrict__ wvp, const float* __restrict__ bv,
    ushort* __restrict__ kpk, ushort* __restrict__ vpk) {
  const int b = blockIdx.x;
  const int t = threadIdx.x;
  __shared__ ushort xsb[64 * 264];        // [n][c], stride 264
  __shared__ ushort Cst[2][64 * 264];     // k/v C tiles

  // ---- phase 1: sampling ----
  {
    const int n = t >> 3, c0 = (t & 7) * 32;
    const int g = c0 >> 6;
    const int bg = b * 4 + g;
    float py = pos_ws[bg * 128 + n * 2];
    float px = pos_ws[bg * 128 + n * 2 + 1];
    float gx = (px + 1.f) * 27.5f;
    float gy = (py + 1.f) * 27.5f;
    float x0f = floorf(gx), y0f = floorf(gy);
    int x0 = (int)x0f, y0 = (int)y0f;
    float wx1 = gx - x0f, wx0 = 1.f - wx1;
    float wy1 = gy - y0f, wy0 = 1.f - wy1;
    float v00 = (x0 >= 0 && x0 <= 55 && y0 >= 0 && y0 <= 55) ? 1.f : 0.f;
    float v01 = (x0 + 1 >= 0 && x0 + 1 <= 55 && y0 >= 0 && y0 <= 55) ? 1.f : 0.f;
    float v10 = (x0 >= 0 && x0 <= 55 && y0 + 1 >= 0 && y0 + 1 <= 55) ? 1.f : 0.f;
    float v11 = (x0 + 1 >= 0 && x0 + 1 <= 55 && y0 + 1 >= 0 && y0 + 1 <= 55) ? 1.f : 0.f;
    float w00 = wx0 * wy0 * v00, w01 = wx1 * wy0 * v01;
    float w10 = wx0 * wy1 * v10, w11 = wx1 * wy1 * v11;
    int cx0 = min(max(x0, 0), 55), cx1 = min(max(x0 + 1, 0), 55);
    int cy0 = min(max(y0, 0), 55), cy1 = min(max(y0 + 1, 0), 55);
    const ushort* fb = featb + (size_t)b * 3136 * 256;
    const ushort* p00 = fb + (size_t)(cy0 * 56 + cx0) * 256;
    const ushort* p01 = fb + (size_t)(cy0 * 56 + cx1) * 256;
    const ushort* p10 = fb + (size_t)(cy1 * 56 + cx0) * 256;
    const ushort* p11 = fb + (size_t)(cy1 * 56 + cx1) * 256;
#pragma unroll
    for (int q4 = 0; q4 < 4; q4++) {
      const int c = c0 + q4 * 8;
      bf16x8 a00 = *(const bf16x8*)(p00 + c);
      bf16x8 a01 = *(const bf16x8*)(p01 + c);
      bf16x8 a10 = *(const bf16x8*)(p10 + c);
      bf16x8 a11 = *(const bf16x8*)(p11 + c);
      bf16x8 o8;
#pragma unroll
      for (int e = 0; e < 8; e++) {
        float s = bf2f((ushort)a00[e]) * w00 + bf2f((ushort)a01[e]) * w01 +
                  bf2f((ushort)a10[e]) * w10 + bf2f((ushort)a11[e]) * w11;
        o8[e] = (short)f2bf(s);
      }
      *(bf16x8*)(xsb + n * 264 + c) = o8;
    }
  }
  __syncthreads();

  // ---- phase 2: GEMM (wave = (mat, mt)) ----
  const int lane = t & 63, w = t >> 6;
  const int mat = w >> 2, mt = w & 3;
  const int lr = lane & 15, kg = lane >> 4;
  const ushort* wp = mat ? wvp : wkp;
  const float* bs = mat ? bv : bk;
  f32x4 acc[16];
#pragma unroll
  for (int f = 0; f < 16; f++) {
    float bvv = bs[f * 16 + lr];
    acc[f] = (f32x4){bvv, bvv, bvv, bvv};
  }
#pragma unroll
  for (int ks = 0; ks < 8; ks++) {
    bf16x8 a = *(const bf16x8*)(xsb + (mt * 16 + lr) * 264 + ks * 32 + kg * 8);
#pragma unroll
    for (int f = 0; f < 16; f++) {
      bf16x8 bfr = *(const bf16x8*)(wp + (size_t)((ks * 4 + kg) * 256 + f * 16 + lr) * 8);
      acc[f] = __builtin_amdgcn_mfma_f32_16x16x32_bf16(a, bfr, acc[f], 0, 0, 0);
    }
  }
  ushort* cst = Cst[mat];
#pragma unroll
  for (int f = 0; f < 16; f++)
#pragma unroll
    for (int j = 0; j < 4; j++)
      cst[(mt * 16 + kg * 4 + j) * 264 + f * 16 + lr] = f2bf(acc[f][j]);
  __syncthreads();

  // ---- epilogue: frag packs ----
#pragma unroll
  for (int pass = 0; pass < 4; pass++) {      // kpk [h][c8][n][8]
    int grp = pass * 8 + (t >> 6);
    int h = grp >> 2, c8 = grp & 3, n2 = t & 63;
    bf16x8 v8 = *(const bf16x8*)(Cst[0] + n2 * 264 + h * 32 + c8 * 8);
    *(bf16x8*)(kpk + (size_t)(b * 8 + h) * 2048 + (c8 * 64 + n2) * 8) = v8;
  }
#pragma unroll
  for (int pass = 0; pass < 4; pass++) {      // vpk [h][n8][cc][e=n&7]
    int grp = pass * 512 + t;
    int h = grp >> 8, n8 = (grp >> 5) & 7, cc = grp & 31;
    bf16x8 v8;
#pragma unroll
    for (int e = 0; e < 8; e++)
      v8[e] = (short)Cst[1][(n8 * 8 + e) * 264 + h * 32 + cc];
    *(bf16x8*)(vpk + (size_t)(b * 8 + h) * 2048 + (n8 * 32 + cc) * 8) = v8;
  }
}

// ---------------------------------------------------------------------------
// Kernel F: MFMA attention. Block = (b, g, 64-query tile); 4 waves x 16 q.
// Bias MLP per-thread in C-fragment layout, packed half2 math.
__global__ __launch_bounds__(256) void k_attn_mfma(
    const ushort* __restrict__ qpk, const ushort* __restrict__ kpk,
    const ushort* __restrict__ vpk, const float* __restrict__ pos_ws,
    const float* __restrict__ w1, const float* __restrict__ b1,
    const float* __restrict__ w2, ushort* __restrict__ attnpk) {
  const int bg = blockIdx.y;           // b*4+g
  const int b = bg >> 2, g = bg & 3;
  const int m0 = blockIdx.x * 64;
  const int t = threadIdx.x;
  const int lane = t & 63, w = t >> 6;
  const int lr = lane & 15, kg = lane >> 4;

  __shared__ ushort Pbuf[4][16 * 72];  // per-wave P staging
  __shared__ ushort outb[64 * 72];     // epilogue tile
  __shared__ float posl[128];
  __shared__ __half2 rpeh[32][6];      // {w1y,w1x,b1,w2a,w2b} broadcast pairs

  if (t < 128) posl[t] = pos_ws[bg * 128 + t];
  if (t < 32) {
    rpeh[t][0] = __float2half2_rn(w1[t * 2]);
    rpeh[t][1] = __float2half2_rn(w1[t * 2 + 1]);
    rpeh[t][2] = __float2half2_rn(b1[t]);
    rpeh[t][3] = __float2half2_rn(w2[t]);
    rpeh[t][4] = __float2half2_rn(w2[32 + t]);
  }
  __syncthreads();

  // --- bias MLP (pair p = nf*4+j -> row kg*4+j, col nf*16+lr) ---
  float qgy[4], qgx[4];
#pragma unroll
  for (int j = 0; j < 4; j++) {
    int m = m0 + w * 16 + kg * 4 + j;
    int my = m / 56, mx = m % 56;
    qgy[j] = (float)my * (56.0f / 55.0f) * (2.0f / 55.0f) - 1.0f;
    qgx[j] = (float)mx * (56.0f / 55.0f) * (2.0f / 55.0f) - 1.0f;
  }
  float tyv[16], txv[16];
#pragma unroll
  for (int nf = 0; nf < 4; nf++) {
    int n = nf * 16 + lr;
    float py = posl[2 * n], px = posl[2 * n + 1];
#pragma unroll
    for (int j = 0; j < 4; j++) {
      float dy = (qgy[j] - py) * 4.f;
      float dx = (qgx[j] - px) * 4.f;
      tyv[nf * 4 + j] = copysignf(__log2f(fabsf(dy) + 1.f) * (1.f / 3.f), dy);
      txv[nf * 4 + j] = copysignf(__log2f(fabsf(dx) + 1.f) * (1.f / 3.f), dx);
    }
  }
  __half2 ty2[8], tx2[8], bb02[8], bb12[8];
  const __half2 z2 = __float2half2_rn(0.f);
#pragma unroll
  for (int k = 0; k < 8; k++) {
    ty2[k] = __floats2half2_rn(tyv[2 * k], tyv[2 * k + 1]);
    tx2[k] = __floats2half2_rn(txv[2 * k], txv[2 * k + 1]);
    bb02[k] = z2; bb12[k] = z2;
  }
  for (int jj = 0; jj < 32; jj++) {
    __half2 hy = rpeh[jj][0], hx = rpeh[jj][1], hb = rpeh[jj][2];
    __half2 ha = rpeh[jj][3], hc = rpeh[jj][4];
#pragma unroll
    for (int k = 0; k < 8; k++) {
      __half2 h = __hfma2(hy, ty2[k], __hfma2(hx, tx2[k], hb));
      h = h2max(h, z2);
      bb02[k] = __hfma2(ha, h, bb02[k]);
      bb12[k] = __hfma2(hc, h, bb12[k]);
    }
  }
  float bb0[16], bb1[16];
#pragma unroll
  for (int k = 0; k < 8; k++) {
    float2 f0 = __half22float2(bb02[k]);
    float2 f1 = __half22float2(bb12[k]);
    bb0[2 * k] = f0.x; bb0[2 * k + 1] = f0.y;
    bb1[2 * k] = f1.x; bb1[2 * k + 1] = f1.y;
  }

  const int mrow = m0 + w * 16 + lr;
  const float scale = 0.17677669529663687f;   // 1/sqrt(32)
  ushort* pb = Pbuf[w];

  f32x4 oacc[2][2];
#pragma unroll
  for (int gh = 0; gh < 2; gh++)
#pragma unroll
    for (int cf = 0; cf < 2; cf++) oacc[gh][cf] = (f32x4){0.f, 0.f, 0.f, 0.f};

#pragma unroll
  for (int gh = 0; gh < 2; gh++) {
    bf16x8 a = *(const bf16x8*)(qpk +
        ((size_t)(b * 3136 + mrow) * 256 + g * 64 + gh * 32 + kg * 8));
    const ushort* kbase = kpk + (size_t)(b * 8 + g * 2 + gh) * 2048;
    f32x4 s[4];
#pragma unroll
    for (int nf = 0; nf < 4; nf++) {
      bf16x8 bfr = *(const bf16x8*)(kbase + (size_t)(kg * 64 + nf * 16 + lr) * 8);
      s[nf] = __builtin_amdgcn_mfma_f32_16x16x32_bf16(
          a, bfr, (f32x4){0.f, 0.f, 0.f, 0.f}, 0, 0, 0);
    }
#pragma unroll
    for (int nf = 0; nf < 4; nf++)
#pragma unroll
      for (int j = 0; j < 4; j++)
        s[nf][j] = fmaf(s[nf][j], scale,
                        gh ? bb1[nf * 4 + j] : bb0[nf * 4 + j]);
#pragma unroll
    for (int j = 0; j < 4; j++) {
      float m1 = fmaxf(fmaxf(s[0][j], s[1][j]), fmaxf(s[2][j], s[3][j]));
#pragma unroll
      for (int o = 8; o >= 1; o >>= 1) m1 = fmaxf(m1, __shfl_xor(m1, o));
      float ss = 0.f;
#pragma unroll
      for (int nf = 0; nf < 4; nf++) {
        float e = __expf(s[nf][j] - m1);
        s[nf][j] = e;
        ss += e;
      }
#pragma unroll
      for (int o = 8; o >= 1; o >>= 1) ss += __shfl_xor(ss, o);
      float inv = 1.f / ss;
#pragma unroll
      for (int nf = 0; nf < 4; nf++) s[nf][j] *= inv;
    }
#pragma unroll
    for (int nf = 0; nf < 4; nf++)
#pragma unroll
      for (int j = 0; j < 4; j++)
        pb[(kg * 4 + j) * 72 + nf * 16 + lr] = f2bf(s[nf][j]);
    const ushort* vbase = vpk + (size_t)(b * 8 + g * 2 + gh) * 2048;
#pragma unroll
    for (int ks = 0; ks < 2; ks++) {
      bf16x8 pa = *(const bf16x8*)(pb + lr * 72 + ks * 32 + kg * 8);
#pragma unroll
      for (int cf = 0; cf < 2; cf++) {
        bf16x8 vb = *(const bf16x8*)(vbase +
            (size_t)((ks * 4 + kg) * 32 + cf * 16 + lr) * 8);
        oacc[gh][cf] = __builtin_amdgcn_mfma_f32_16x16x32_bf16(
            pa, vb, oacc[gh][cf], 0, 0, 0);
      }
    }
  }

#pragma unroll
  for (int gh = 0; gh < 2; gh++)
#pragma unroll
    for (int cf = 0; cf < 2; cf++)
#pragma unroll
      for (int j = 0; j < 4; j++)
        outb[(w * 16 + kg * 4 + j) * 72 + gh * 32 + cf * 16 + lr] =
            f2bf(oacc[gh][cf][j]);
  __syncthreads();
#pragma unroll
  for (int r2 = 0; r2 < 2; r2++) {
    int row = (t >> 3) + r2 * 32;
    int chunk = t & 7;
    bf16x8 v8 = *(const bf16x8*)(outb + row * 72 + chunk * 8);
    *(bf16x8*)(attnpk +
               ((size_t)(b * 3136 + m0 + row) * 256 + g * 64 + chunk * 8)) = v8;
  }
}

// ---------------------------------------------------------------------------
extern "C" void kernel_launch(void* const* d_in, const int* in_sizes, int n_in,
                              void* d_out, int out_size, void* d_ws,
                              size_t ws_size, hipStream_t stream) {
  const float* x       = (const float*)d_in[0];
  const float* patch_w = (const float*)d_in[1];
  const float* patch_b = (const float*)d_in[2];
  const float* ln1_g   = (const float*)d_in[3];
  const float* ln1_b   = (const float*)d_in[4];
  const float* wq      = (const float*)d_in[5];
  const float* bq      = (const float*)d_in[6];
  const float* wk      = (const float*)d_in[7];
  const float* bk      = (const float*)d_in[8];
  const float* wv      = (const float*)d_in[9];
  const float* bv      = (const float*)d_in[10];
  const float* wo      = (const float*)d_in[11];
  const float* bo      = (const float*)d_in[12];
  const float* off_dw_w = (const float*)d_in[13];
  const float* off_dw_b = (const float*)d_in[14];
  const float* off_ln_g = (const float*)d_in[15];
  const float* off_ln_b = (const float*)d_in[16];
  const float* off_pw_w = (const float*)d_in[17];
  const float* rpe_w1  = (const float*)d_in[18];
  const float* rpe_b1  = (const float*)d_in[19];
  const float* rpe_w2  = (const float*)d_in[20];

  float* ws = (float*)d_ws;
  ushort* featb = (ushort*)(ws + OFF_FEATB);   // bf16 [m][c]
  ushort* attnpk = featb;                      // reuse (feat dead after sample)
  ushort* qpk = (ushort*)(ws + OFF_QPK);       // bf16 [m][c]
  float* q    = ws + OFF_Q;                    // fp32 [c][m]
  ushort* xb  = (ushort*)(ws + OFF_Q);         // bf16 x (dead before q written)
  float* posw = ws + OFF_POS;
  float* convo = ws + OFF_XS;
  ushort* kpk = (ushort*)(ws + OFF_KPK);
  ushort* vpk = (ushort*)(ws + OFF_VPK);
  ushort* pwp = (ushort*)(ws + OFF_PWP);
  ushort* wqp = (ushort*)(ws + OFF_WQP);
  ushort* wop = (ushort*)(ws + OFF_WOP);
  ushort* wkp = (ushort*)(ws + OFF_WKP);
  ushort* wvp = (ushort*)(ws + OFF_WVP);

  float* y = (float*)d_out;
  float* out_pos = y + 6422528;
  float* out_ref = out_pos + 4096;

  // X: x -> bf16 (4816896 elems = 2352 * 2048)
  hipLaunchKernelGGL(k_xcvt, dim3(2352), dim3(256), 0, stream, x, xb);
  // P: weight packs
  hipLaunchKernelGGL(k_pack, dim3(256, 5), dim3(256), 0, stream,
                     patch_w, wq, wk, wv, wo, pwp, wqp, wkp, wvp, wop);
  // A: patch embed conv (MFMA, staged B) + LN -> feat bf16 [m][c]
  hipLaunchKernelGGL(k_patch_mfma, dim3(196), dim3(256), 0, stream,
                     xb, pwp, patch_b, ln1_g, ln1_b, featb);
  // B: q = wq @ feat + bq  -> fp32 [c][m] + bf16 pack [m][c]
  hipLaunchKernelGGL(k_gemm_mfma, dim3(196), dim3(256), 0, stream,
                     featb, wqp, bq, q, qpk);
  // C1: offset depthwise conv
  hipLaunchKernelGGL(k_offset_conv, dim3(32, 32), dim3(128), 0, stream,
                     q, off_dw_w, convo);
  // C2: offset post (LN + GELU + pointwise + tanh) -> pos
  hipLaunchKernelGGL(k_offset_post, dim3(16, 32), dim3(256), 0, stream,
                     convo, off_dw_b, off_ln_g, off_ln_b, off_pw_w,
                     posw, out_pos, out_ref);
  // DE: fused sampling + k,v MFMA projections -> frag packs
  hipLaunchKernelGGL(k_sample_kv, dim3(8), dim3(512), 0, stream,
                     featb, posw, wkp, bk, wvp, bv, kpk, vpk);
  // F: MFMA attention -> bf16 pack [m][c]
  hipLaunchKernelGGL(k_attn_mfma, dim3(49, 32), dim3(256), 0, stream,
                     qpk, kpk, vpk, posw, rpe_w1, rpe_b1, rpe_w2, attnpk);
  // G: y = wo @ attn_out + bo  (fp32 [c][m] = d_out)
  hipLaunchKernelGGL(k_gemm_mfma, dim3(196), dim3(256), 0, stream,
                     attnpk, wop, bo, y, (ushort*)nullptr);
}

// Round 11
// 249.731 us; speedup vs baseline: 1.1192x; 1.1192x over previous
//
#include <hip/hip_runtime.h>
#include <cstddef>

// Problem constants
// B=8, DIM=256, NH=8, H=W=56, G=4, CG=64, GH=2, HC=32, Hk=Wk=8, ns=64

typedef short bf16x8 __attribute__((ext_vector_type(8)));
typedef float f32x4 __attribute__((ext_vector_type(4)));

static __device__ __forceinline__ ushort f2bf(float f) {
  union { float f; unsigned u; } v; v.f = f;
  unsigned r = v.u + 0x7fffu + ((v.u >> 16) & 1u);   // RNE
  return (ushort)(r >> 16);
}
static __device__ __forceinline__ float bf2f(ushort u) {
  union { unsigned u; float f; } v; v.u = ((unsigned)u) << 16;
  return v.f;
}

// ws float offsets
#define OFF_FEATB 0u          // feat bf16 [b*3136+m][256c] (later reused as attnpk)
#define OFF_QPK   3211264u    // q bf16 [b*3136+m][256c]
#define OFF_Q     6422528u    // q fp32 [b][c][m]; ALSO aliased as xb bf16 (earlier)
#define OFF_POS   12845056u   // 4096
#define OFF_XS    12849152u   // 131072 (offset-conv scratch)
#define OFF_KPK   12980224u   // K bf16 pack [b][h][c8=4][n=64][8]
#define OFF_VPK   13045760u   // V bf16 pack [b][h][n8=8][c=32][8]
#define OFF_PWP   13111296u   // pw pack 49152 bf16 = 24576 fl
#define OFF_WQP   13135872u   // 65536 bf16 = 32768 fl
#define OFF_WOP   13168640u   // 32768 fl
#define OFF_WKT   13201408u   // 65536 fl (fp32 wk^T)
#define OFF_WVT   13266944u   // 65536 fl -> end 13332480 fl (53.3 MB)

// ---------------------------------------------------------------------------
// Kernel X: convert x fp32 -> bf16 (same layout).  4816896 elements.
__global__ __launch_bounds__(256) void k_xcvt(
    const float* __restrict__ x, ushort* __restrict__ xb) {
  const size_t i0 = ((size_t)blockIdx.x * 256 + threadIdx.x) * 8;
  float4 v0 = *(const float4*)(x + i0);
  float4 v1 = *(const float4*)(x + i0 + 4);
  bf16x8 o;
  o[0] = (short)f2bf(v0.x); o[1] = (short)f2bf(v0.y);
  o[2] = (short)f2bf(v0.z); o[3] = (short)f2bf(v0.w);
  o[4] = (short)f2bf(v1.x); o[5] = (short)f2bf(v1.y);
  o[6] = (short)f2bf(v1.z); o[7] = (short)f2bf(v1.w);
  *(bf16x8*)(xb + i0) = o;
}

// ---------------------------------------------------------------------------
// Kernel P: pack weights. m=0 pwp, 1 wqp, 2 wop (bf16 frag packs [k8][o][8]);
// m=3 wkT, m=4 wvT (fp32 transposed [c][o]).
__global__ __launch_bounds__(256) void k_pack(
    const float* __restrict__ pw, const float* __restrict__ wq,
    const float* __restrict__ wk, const float* __restrict__ wv,
    const float* __restrict__ wo, ushort* __restrict__ pwp,
    ushort* __restrict__ wqp, ushort* __restrict__ wop,
    float* __restrict__ wkT, float* __restrict__ wvT) {
  const int o = blockIdx.x, t = threadIdx.x, m = blockIdx.y;
  if (m == 0) {
    if (t < 192) pwp[((t >> 3) * 256 + o) * 8 + (t & 7)] = f2bf(pw[o * 192 + t]);
  } else if (m == 1) {
    wqp[((t >> 3) * 256 + o) * 8 + (t & 7)] = f2bf(wq[o * 256 + t]);
  } else if (m == 2) {
    wop[((t >> 3) * 256 + o) * 8 + (t & 7)] = f2bf(wo[o * 256 + t]);
  } else if (m == 3) {
    wkT[t * 256 + o] = wk[o * 256 + t];
  } else {
    wvT[t * 256 + o] = wv[o * 256 + t];
  }
}

// ---------------------------------------------------------------------------
// Kernel A: patch conv (im2col MFMA, K=192) + bias + channel-LN -> bf16 [m][c]
// Block = 4 waves x 32 rows = 128 rows; B slices (16KB) LDS double-buffered.
__global__ __launch_bounds__(256) void k_patch_mfma(
    const ushort* __restrict__ xb, const ushort* __restrict__ pwp,
    const float* __restrict__ pb, const float* __restrict__ g1,
    const float* __restrict__ b1, ushort* __restrict__ featb) {
  __shared__ ushort Bs[2][8192];
  const int t = threadIdx.x;
  const int lane = t & 63, w = t >> 6;
  const int lr = lane & 15, kg = lane >> 4;
  const int m_base = blockIdx.x * 128 + w * 32;

  size_t abase[2];
#pragma unroll
  for (int mr = 0; mr < 2; mr++) {
    int mA = m_base + mr * 16 + lr;
    int bA = mA / 3136;
    int posA = mA - bA * 3136;
    int ohA = posA / 56;
    int owA = posA - ohA * 56;
    abase[mr] = (((size_t)bA * 3) * 448 + ohA * 8) * 448 + owA * 8;
  }

  f32x4 acc[2][16];
#pragma unroll
  for (int f = 0; f < 16; f++) {
    float bv = pb[f * 16 + lr];
    acc[0][f] = (f32x4){bv, bv, bv, bv};
    acc[1][f] = (f32x4){bv, bv, bv, bv};
  }

  bf16x8 st[4];
#pragma unroll
  for (int i = 0; i < 4; i++)
    st[i] = *(const bf16x8*)(pwp + i * 2048 + t * 8);
#pragma unroll
  for (int i = 0; i < 4; i++)
    *(bf16x8*)(&Bs[0][i * 2048 + t * 8]) = st[i];
  __syncthreads();
  int p = 0;
  for (int ks = 0; ks < 6; ks++) {
    if (ks < 5) {
#pragma unroll
      for (int i = 0; i < 4; i++)
        st[i] = *(const bf16x8*)(pwp + (ks + 1) * 8192 + i * 2048 + t * 8);
    }
    const int k8 = ks * 4 + kg;
    const int ci = k8 >> 3, ii = k8 & 7;
    bf16x8 a0 = *(const bf16x8*)(xb + abase[0] + (size_t)ci * 200704 + ii * 448);
    bf16x8 a1 = *(const bf16x8*)(xb + abase[1] + (size_t)ci * 200704 + ii * 448);
    const ushort* bsl = &Bs[p][kg * 2048];
#pragma unroll
    for (int f = 0; f < 16; f++) {
      bf16x8 bfr = *(const bf16x8*)(bsl + (f * 16 + lr) * 8);
      acc[0][f] = __builtin_amdgcn_mfma_f32_16x16x32_bf16(a0, bfr, acc[0][f], 0, 0, 0);
      acc[1][f] = __builtin_amdgcn_mfma_f32_16x16x32_bf16(a1, bfr, acc[1][f], 0, 0, 0);
    }
    __syncthreads();
    if (ks < 5) {
#pragma unroll
      for (int i = 0; i < 4; i++)
        *(bf16x8*)(&Bs[p ^ 1][i * 2048 + t * 8]) = st[i];
      __syncthreads();
      p ^= 1;
    }
  }

#pragma unroll
  for (int mr = 0; mr < 2; mr++) {
    float mean[4], rstd[4];
#pragma unroll
    for (int j = 0; j < 4; j++) {
      float s1 = 0.f, s2 = 0.f;
#pragma unroll
      for (int f = 0; f < 16; f++) { float v = acc[mr][f][j]; s1 += v; s2 += v * v; }
#pragma unroll
      for (int off = 8; off >= 1; off >>= 1) {
        s1 += __shfl_xor(s1, off);
        s2 += __shfl_xor(s2, off);
      }
      float mn = s1 * (1.f / 256.f);
      float var = s2 * (1.f / 256.f) - mn * mn;
      mean[j] = mn; rstd[j] = rsqrtf(var + 1e-5f);
    }
#pragma unroll
    for (int f = 0; f < 16; f++) {
      const int c = f * 16 + lr;
      const float gg = g1[c], bb = b1[c];
#pragma unroll
      for (int j = 0; j < 4; j++) {
        const int mo = m_base + mr * 16 + kg * 4 + j;
        float v = (acc[mr][f][j] - mean[j]) * rstd[j] * gg + bb;
        featb[(size_t)mo * 256 + c] = f2bf(v);
      }
    }
  }
}

// ---------------------------------------------------------------------------
// Kernel B: MFMA GEMM, 128 rows/block (4 waves x 32), B staged in LDS.
__global__ __launch_bounds__(256) void k_gemm_mfma(
    const ushort* __restrict__ apk, const ushort* __restrict__ wp,
    const float* __restrict__ bias, float* __restrict__ out,
    ushort* __restrict__ opk) {
  __shared__ float smem[16448];           // 65792 B: Bs (32KB) / sA 64x257 f32
  ushort* Bs = (ushort*)smem;
  float* sA = smem;
  const int t = threadIdx.x;
  const int lane = t & 63, w = t >> 6;
  const int lr = lane & 15, kg = lane >> 4;
  const int m_base = blockIdx.x * 128 + w * 32;

  f32x4 acc[2][16];
#pragma unroll
  for (int f = 0; f < 16; f++) {
    float bv = bias[f * 16 + lr];
    acc[0][f] = (f32x4){bv, bv, bv, bv};
    acc[1][f] = (f32x4){bv, bv, bv, bv};
  }
  const ushort* a0p = apk + (size_t)(m_base + lr) * 256;
  const ushort* a1p = a0p + 16 * 256;

  bf16x8 st[4];
#pragma unroll
  for (int i = 0; i < 4; i++) st[i] = *(const bf16x8*)(wp + i * 2048 + t * 8);
#pragma unroll
  for (int i = 0; i < 4; i++) *(bf16x8*)(Bs + i * 2048 + t * 8) = st[i];
  __syncthreads();
  int p = 0;
  for (int ks = 0; ks < 8; ks++) {
    if (ks < 7) {
#pragma unroll
      for (int i = 0; i < 4; i++)
        st[i] = *(const bf16x8*)(wp + (ks + 1) * 8192 + i * 2048 + t * 8);
    }
    bf16x8 a0 = *(const bf16x8*)(a0p + ks * 32 + kg * 8);
    bf16x8 a1 = *(const bf16x8*)(a1p + ks * 32 + kg * 8);
    const ushort* bsl = Bs + p * 8192 + kg * 2048;
#pragma unroll
    for (int f = 0; f < 16; f++) {
      bf16x8 bfr = *(const bf16x8*)(bsl + (f * 16 + lr) * 8);
      acc[0][f] = __builtin_amdgcn_mfma_f32_16x16x32_bf16(a0, bfr, acc[0][f], 0, 0, 0);
      acc[1][f] = __builtin_amdgcn_mfma_f32_16x16x32_bf16(a1, bfr, acc[1][f], 0, 0, 0);
    }
    __syncthreads();
    if (ks < 7) {
#pragma unroll
      for (int i = 0; i < 4; i++)
        *(bf16x8*)(Bs + (p ^ 1) * 8192 + i * 2048 + t * 8) = st[i];
      __syncthreads();
      p ^= 1;
    }
  }
  __syncthreads();                         // reclaim smem for epilogue

#pragma unroll
  for (int h = 0; h < 2; h++) {
    if ((w >> 1) == h) {
      const int loc0 = (w & 1) * 32;
#pragma unroll
      for (int mr = 0; mr < 2; mr++)
#pragma unroll
        for (int f = 0; f < 16; f++)
#pragma unroll
          for (int j = 0; j < 4; j++)
            sA[(loc0 + mr * 16 + kg * 4 + j) * 257 + f * 16 + lr] = acc[mr][f][j];
    }
    __syncthreads();
    const int R0 = blockIdx.x * 128 + h * 64;
    const int bh = R0 / 3136;
    const int pos0 = R0 % 3136;            // multiple of 64
    {
      const int c = t;
      float* op = out + ((size_t)bh * 256 + c) * 3136 + pos0;
#pragma unroll
      for (int i4 = 0; i4 < 16; i4++) {
        float4 v;
        v.x = sA[(i4 * 4 + 0) * 257 + c];
        v.y = sA[(i4 * 4 + 1) * 257 + c];
        v.z = sA[(i4 * 4 + 2) * 257 + c];
        v.w = sA[(i4 * 4 + 3) * 257 + c];
        *(float4*)(op + i4 * 4) = v;
      }
    }
    if (opk) {
      const int mm = t & 63, cs = t >> 6;
      const int c0 = cs * 64;
#pragma unroll
      for (int jj = 0; jj < 8; jj++) {
        bf16x8 v8;
#pragma unroll
        for (int e = 0; e < 8; e++)
          v8[e] = (short)f2bf(sA[mm * 257 + c0 + jj * 8 + e]);
        *(bf16x8*)(opk + (size_t)(R0 + mm) * 256 + c0 + jj * 8) = v8;
      }
    }
    __syncthreads();
  }
}

// ---------------------------------------------------------------------------
// Kernel C1: offset depthwise conv (28x28, stride 8, pad 14).
__global__ __launch_bounds__(128) void k_offset_conv(
    const float* __restrict__ q, const float* __restrict__ dww,
    float* __restrict__ convo) {
  const int bg = blockIdx.y;
  const int wv = threadIdx.x >> 6;
  const int lane = threadIdx.x & 63;
  const int ch = blockIdx.x * 2 + wv;
  const int b = bg >> 2, g = bg & 3;

  __shared__ float pl[2][7072];
  float* P = pl[wv];
  for (int idx = lane; idx < 7072; idx += 64) P[idx] = 0.f;

  const float* qb = q + ((size_t)b * 256 + g * 64 + ch) * 3136;
  if (lane < 56) {
    for (int r = 0; r < 56; r++) {
      int hr = r + 14;
      P[hr * 84 + (lane + 14) + (hr >> 3)] = qb[r * 56 + lane];
    }
  }
  const int oh = lane >> 3, ow = lane & 7;
  const int chs = __builtin_amdgcn_readfirstlane(ch);
  const float* wr = dww + (size_t)chs * 784;
  float acc = 0.f;
  const int r0 = oh * 8, c0 = ow * 8;
  for (int i = 0; i < 28; i++) {
    int hr = r0 + i;
    const float* prow = P + hr * 84 + c0 + (hr >> 3);
    const float* wrr = wr + i * 28;
#pragma unroll
    for (int j = 0; j < 28; j++)
      acc = fmaf(prow[j], wrr[j], acc);
  }
  convo[bg * 4096 + lane * 64 + ch] = acc;
}

// ---------------------------------------------------------------------------
// Kernel C2: LN(64) + GELU + pointwise(2x64) + tanh + reference points.
__global__ __launch_bounds__(256) void k_offset_post(
    const float* __restrict__ convo, const float* __restrict__ dwb,
    const float* __restrict__ lng, const float* __restrict__ lnb,
    const float* __restrict__ pww, float* __restrict__ pos_ws,
    float* __restrict__ out_pos, float* __restrict__ out_ref) {
  const int bg = blockIdx.y;
  const int wv = threadIdx.x >> 6;
  const int lane = threadIdx.x & 63;
  const int idx = blockIdx.x * 4 + wv;
  const int oh = idx >> 3, ow = idx & 7;

  float acc = convo[bg * 4096 + idx * 64 + lane] + dwb[lane];

  float s1 = acc, s2 = acc * acc;
#pragma unroll
  for (int off = 32; off >= 1; off >>= 1) {
    s1 += __shfl_xor(s1, off);
    s2 += __shfl_xor(s2, off);
  }
  float m = s1 * (1.f / 64.f);
  float var = s2 * (1.f / 64.f) - m * m;
  float val = (acc - m) * rsqrtf(var + 1e-5f) * lng[lane] + lnb[lane];
  val = 0.5f * val * (1.f + erff(val * 0.70710678118654752f));
  float p0 = pww[lane] * val, p1 = pww[64 + lane] * val;
#pragma unroll
  for (int off = 32; off >= 1; off >>= 1) {
    p0 += __shfl_xor(p0, off);
    p1 += __shfl_xor(p1, off);
  }
  if (lane == 0) {
    float offy = tanhf(p0) * (2.0f / 7.0f);
    float offx = tanhf(p1) * (2.0f / 7.0f);
    float ry = (0.5f + oh) * (2.0f / 7.0f) - 1.0f;
    float rx = (0.5f + ow) * (2.0f / 7.0f) - 1.0f;
    float py = offy + ry, px = offx + rx;
    int o = bg * 128 + idx * 2;
    pos_ws[o] = py;  pos_ws[o + 1] = px;
    out_pos[o] = py; out_pos[o + 1] = px;
    out_ref[o] = ry; out_ref[o + 1] = rx;
  }
}

// ---------------------------------------------------------------------------
// Kernel DE: fused bilinear sampling + k,v projections -> bf16 B-frag packs.
// Block (n, b): wave g samples 64 channels of group g; then 256x256 GEMV.
__global__ __launch_bounds__(256) void k_sample_kv(
    const ushort* __restrict__ featb, const float* __restrict__ pos_ws,
    const float* __restrict__ wkT, const float* __restrict__ bk,
    const float* __restrict__ wvT, const float* __restrict__ bv,
    ushort* __restrict__ kpk, ushort* __restrict__ vpk) {
  const int b = blockIdx.y;   // 0..7
  const int n = blockIdx.x;   // 0..63
  const int t = threadIdx.x;
  const int g = t >> 6, lane = t & 63;
  const int bg = b * 4 + g;

  __shared__ float sxs[256];
  {
    float py = pos_ws[bg * 128 + n * 2];
    float px = pos_ws[bg * 128 + n * 2 + 1];
    float gx = (px + 1.f) * 27.5f;
    float gy = (py + 1.f) * 27.5f;
    float x0f = floorf(gx), y0f = floorf(gy);
    int x0 = (int)x0f, y0 = (int)y0f;
    float wx1 = gx - x0f, wx0 = 1.f - wx1;
    float wy1 = gy - y0f, wy0 = 1.f - wy1;
    const size_t mb = (size_t)b * 3136;
    const int cofs = g * 64 + lane;
    float acc = 0.f;
    if (x0 >= 0 && x0 <= 55 && y0 >= 0 && y0 <= 55)
      acc = fmaf(bf2f(featb[(mb + y0 * 56 + x0) * 256 + cofs]), wx0 * wy0, acc);
    if (x0 + 1 >= 0 && x0 + 1 <= 55 && y0 >= 0 && y0 <= 55)
      acc = fmaf(bf2f(featb[(mb + y0 * 56 + x0 + 1) * 256 + cofs]), wx1 * wy0, acc);
    if (x0 >= 0 && x0 <= 55 && y0 + 1 >= 0 && y0 + 1 <= 55)
      acc = fmaf(bf2f(featb[(mb + (y0 + 1) * 56 + x0) * 256 + cofs]), wx0 * wy1, acc);
    if (x0 + 1 >= 0 && x0 + 1 <= 55 && y0 + 1 >= 0 && y0 + 1 <= 55)
      acc = fmaf(bf2f(featb[(mb + (y0 + 1) * 56 + x0 + 1) * 256 + cofs]), wx1 * wy1, acc);
    sxs[g * 64 + lane] = acc;
  }
  __syncthreads();

  float ak = bk[t], av = bv[t];
  for (int c = 0; c < 256; c++) {
    float xv = sxs[c];
    ak = fmaf(wkT[c * 256 + t], xv, ak);
    av = fmaf(wvT[c * 256 + t], xv, av);
  }
  const int h = t >> 5, cc = t & 31;
  const size_t base = (size_t)(b * 8 + h) * 2048;
  kpk[base + (size_t)((cc >> 3) * 64 + n) * 8 + (cc & 7)] = f2bf(ak);
  vpk[base + (size_t)((n >> 3) * 32 + cc) * 8 + (n & 7)] = f2bf(av);
}

// ---------------------------------------------------------------------------
// Kernel F: MFMA attention. Block = (b, g, 64-query tile); 4 waves x 16 q.
// Bias MLP per-thread in C-fragment layout, fp32 registers. Pbuf stride 88
// (176B rows): ds_read_b128 slot = (11*lr + kg) % 8 is uniform -> conflict-free.
__global__ __launch_bounds__(256) void k_attn_mfma(
    const ushort* __restrict__ qpk, const ushort* __restrict__ kpk,
    const ushort* __restrict__ vpk, const float* __restrict__ pos_ws,
    const float* __restrict__ w1, const float* __restrict__ b1,
    const float* __restrict__ w2, ushort* __restrict__ attnpk) {
  const int bg = blockIdx.y;           // b*4+g
  const int b = bg >> 2, g = bg & 3;
  const int m0 = blockIdx.x * 64;
  const int t = threadIdx.x;
  const int lane = t & 63, w = t >> 6;
  const int lr = lane & 15, kg = lane >> 4;

  __shared__ ushort Pbuf[4][16 * 88];  // per-wave P staging, stride 88
  __shared__ ushort outb[64 * 72];     // epilogue tile
  __shared__ float posl[128];
  __shared__ float4 rpe4[32];          // {w1y, w1x, b1, w2[0]}
  __shared__ float rpeB[32];           // w2[1]

  if (t < 128) posl[t] = pos_ws[bg * 128 + t];
  if (t < 32) {
    rpe4[t] = make_float4(w1[t * 2], w1[t * 2 + 1], b1[t], w2[t]);
    rpeB[t] = w2[32 + t];
  }
  __syncthreads();

  // --- bias MLP (fp32 registers, C-layout: pair p = nf*4+j ->
  //     row kg*4+j (query m0+w*16+...), col nf*16+lr (point n)) ---
  float qgy[4], qgx[4];
#pragma unroll
  for (int j = 0; j < 4; j++) {
    int m = m0 + w * 16 + kg * 4 + j;
    int my = m / 56, mx = m % 56;
    qgy[j] = (float)my * (56.0f / 55.0f) * (2.0f / 55.0f) - 1.0f;
    qgx[j] = (float)mx * (56.0f / 55.0f) * (2.0f / 55.0f) - 1.0f;
  }
  float tyv[16], txv[16];
#pragma unroll
  for (int nf = 0; nf < 4; nf++) {
    int n = nf * 16 + lr;
    float py = posl[2 * n], px = posl[2 * n + 1];
#pragma unroll
    for (int j = 0; j < 4; j++) {
      float dy = (qgy[j] - py) * 4.f;
      float dx = (qgx[j] - px) * 4.f;
      tyv[nf * 4 + j] = copysignf(__log2f(fabsf(dy) + 1.f) * (1.f / 3.f), dy);
      txv[nf * 4 + j] = copysignf(__log2f(fabsf(dx) + 1.f) * (1.f / 3.f), dx);
    }
  }
  float bb0[16], bb1[16];
#pragma unroll
  for (int p = 0; p < 16; p++) { bb0[p] = 0.f; bb1[p] = 0.f; }
  for (int jj = 0; jj < 32; jj++) {
    float4 r = rpe4[jj];
    float wb = rpeB[jj];
#pragma unroll
    for (int p = 0; p < 16; p++) {
      float hv = fmaxf(fmaf(r.x, tyv[p], fmaf(r.y, txv[p], r.z)), 0.f);
      bb0[p] = fmaf(r.w, hv, bb0[p]);
      bb1[p] = fmaf(wb, hv, bb1[p]);
    }
  }

  const int mrow = m0 + w * 16 + lr;
  const float scale = 0.17677669529663687f;   // 1/sqrt(32)
  ushort* pb = Pbuf[w];

  f32x4 oacc[2][2];
#pragma unroll
  for (int gh = 0; gh < 2; gh++)
#pragma unroll
    for (int cf = 0; cf < 2; cf++) oacc[gh][cf] = (f32x4){0.f, 0.f, 0.f, 0.f};

#pragma unroll
  for (int gh = 0; gh < 2; gh++) {
    bf16x8 a = *(const bf16x8*)(qpk +
        ((size_t)(b * 3136 + mrow) * 256 + g * 64 + gh * 32 + kg * 8));
    const ushort* kbase = kpk + (size_t)(b * 8 + g * 2 + gh) * 2048;
    f32x4 s[4];
#pragma unroll
    for (int nf = 0; nf < 4; nf++) {
      bf16x8 bfr = *(const bf16x8*)(kbase + (size_t)(kg * 64 + nf * 16 + lr) * 8);
      s[nf] = __builtin_amdgcn_mfma_f32_16x16x32_bf16(
          a, bfr, (f32x4){0.f, 0.f, 0.f, 0.f}, 0, 0, 0);
    }
#pragma unroll
    for (int nf = 0; nf < 4; nf++)
#pragma unroll
      for (int j = 0; j < 4; j++)
        s[nf][j] = fmaf(s[nf][j], scale,
                        gh ? bb1[nf * 4 + j] : bb0[nf * 4 + j]);
#pragma unroll
    for (int j = 0; j < 4; j++) {
      float m1 = fmaxf(fmaxf(s[0][j], s[1][j]), fmaxf(s[2][j], s[3][j]));
#pragma unroll
      for (int o = 8; o >= 1; o >>= 1) m1 = fmaxf(m1, __shfl_xor(m1, o));
      float ss = 0.f;
#pragma unroll
      for (int nf = 0; nf < 4; nf++) {
        float e = __expf(s[nf][j] - m1);
        s[nf][j] = e;
        ss += e;
      }
#pragma unroll
      for (int o = 8; o >= 1; o >>= 1) ss += __shfl_xor(ss, o);
      float inv = 1.f / ss;
#pragma unroll
      for (int nf = 0; nf < 4; nf++) s[nf][j] *= inv;
    }
#pragma unroll
    for (int nf = 0; nf < 4; nf++)
#pragma unroll
      for (int j = 0; j < 4; j++)
        pb[(kg * 4 + j) * 88 + nf * 16 + lr] = f2bf(s[nf][j]);
    const ushort* vbase = vpk + (size_t)(b * 8 + g * 2 + gh) * 2048;
#pragma unroll
    for (int ks = 0; ks < 2; ks++) {
      bf16x8 pa = *(const bf16x8*)(pb + lr * 88 + ks * 32 + kg * 8);
#pragma unroll
      for (int cf = 0; cf < 2; cf++) {
        bf16x8 vb = *(const bf16x8*)(vbase +
            (size_t)((ks * 4 + kg) * 32 + cf * 16 + lr) * 8);
        oacc[gh][cf] = __builtin_amdgcn_mfma_f32_16x16x32_bf16(
            pa, vb, oacc[gh][cf], 0, 0, 0);
      }
    }
  }

#pragma unroll
  for (int gh = 0; gh < 2; gh++)
#pragma unroll
    for (int cf = 0; cf < 2; cf++)
#pragma unroll
      for (int j = 0; j < 4; j++)
        outb[(w * 16 + kg * 4 + j) * 72 + gh * 32 + cf * 16 + lr] =
            f2bf(oacc[gh][cf][j]);
  __syncthreads();
#pragma unroll
  for (int r2 = 0; r2 < 2; r2++) {
    int row = (t >> 3) + r2 * 32;
    int chunk = t & 7;
    bf16x8 v8 = *(const bf16x8*)(outb + row * 72 + chunk * 8);
    *(bf16x8*)(attnpk +
               ((size_t)(b * 3136 + m0 + row) * 256 + g * 64 + chunk * 8)) = v8;
  }
}

// ---------------------------------------------------------------------------
extern "C" void kernel_launch(void* const* d_in, const int* in_sizes, int n_in,
                              void* d_out, int out_size, void* d_ws,
                              size_t ws_size, hipStream_t stream) {
  const float* x       = (const float*)d_in[0];
  const float* patch_w = (const float*)d_in[1];
  const float* patch_b = (const float*)d_in[2];
  const float* ln1_g   = (const float*)d_in[3];
  const float* ln1_b   = (const float*)d_in[4];
  const float* wq      = (const float*)d_in[5];
  const float* bq      = (const float*)d_in[6];
  const float* wk      = (const float*)d_in[7];
  const float* bk      = (const float*)d_in[8];
  const float* wv      = (const float*)d_in[9];
  const float* bv      = (const float*)d_in[10];
  const float* wo      = (const float*)d_in[11];
  const float* bo      = (const float*)d_in[12];
  const float* off_dw_w = (const float*)d_in[13];
  const float* off_dw_b = (const float*)d_in[14];
  const float* off_ln_g = (const float*)d_in[15];
  const float* off_ln_b = (const float*)d_in[16];
  const float* off_pw_w = (const float*)d_in[17];
  const float* rpe_w1  = (const float*)d_in[18];
  const float* rpe_b1  = (const float*)d_in[19];
  const float* rpe_w2  = (const float*)d_in[20];

  float* ws = (float*)d_ws;
  ushort* featb = (ushort*)(ws + OFF_FEATB);   // bf16 [m][c]
  ushort* attnpk = featb;                      // reuse (feat dead after sample)
  ushort* qpk = (ushort*)(ws + OFF_QPK);       // bf16 [m][c]
  float* q    = ws + OFF_Q;                    // fp32 [c][m]
  ushort* xb  = (ushort*)(ws + OFF_Q);         // bf16 x (dead before q written)
  float* posw = ws + OFF_POS;
  float* convo = ws + OFF_XS;
  ushort* kpk = (ushort*)(ws + OFF_KPK);
  ushort* vpk = (ushort*)(ws + OFF_VPK);
  ushort* pwp = (ushort*)(ws + OFF_PWP);
  ushort* wqp = (ushort*)(ws + OFF_WQP);
  ushort* wop = (ushort*)(ws + OFF_WOP);
  float* wkT  = ws + OFF_WKT;
  float* wvT  = ws + OFF_WVT;

  float* y = (float*)d_out;
  float* out_pos = y + 6422528;
  float* out_ref = out_pos + 4096;

  // X: x -> bf16 (4816896 elems = 2352 * 2048)
  hipLaunchKernelGGL(k_xcvt, dim3(2352), dim3(256), 0, stream, x, xb);
  // P: weight packs / transposes
  hipLaunchKernelGGL(k_pack, dim3(256, 5), dim3(256), 0, stream,
                     patch_w, wq, wk, wv, wo, pwp, wqp, wop, wkT, wvT);
  // A: patch embed conv (MFMA, staged B) + LN -> feat bf16 [m][c]
  hipLaunchKernelGGL(k_patch_mfma, dim3(196), dim3(256), 0, stream,
                     xb, pwp, patch_b, ln1_g, ln1_b, featb);
  // B: q = wq @ feat + bq  -> fp32 [c][m] + bf16 pack [m][c]
  hipLaunchKernelGGL(k_gemm_mfma, dim3(196), dim3(256), 0, stream,
                     featb, wqp, bq, q, qpk);
  // C1: offset depthwise conv
  hipLaunchKernelGGL(k_offset_conv, dim3(32, 32), dim3(128), 0, stream,
                     q, off_dw_w, convo);
  // C2: offset post (LN + GELU + pointwise + tanh) -> pos
  hipLaunchKernelGGL(k_offset_post, dim3(16, 32), dim3(256), 0, stream,
                     convo, off_dw_b, off_ln_g, off_ln_b, off_pw_w,
                     posw, out_pos, out_ref);
  // DE: fused sampling + k,v projections -> bf16 B-frag packs
  hipLaunchKernelGGL(k_sample_kv, dim3(64, 8), dim3(256), 0, stream,
                     featb, posw, wkT, bk, wvT, bv, kpk, vpk);
  // F: MFMA attention -> bf16 pack [m][c]
  hipLaunchKernelGGL(k_attn_mfma, dim3(49, 32), dim3(256), 0, stream,
                     qpk, kpk, vpk, posw, rpe_w1, rpe_b1, rpe_w2, attnpk);
  // G: y = wo @ attn_out + bo  (fp32 [c][m] = d_out)
  hipLaunchKernelGGL(k_gemm_mfma, dim3(196), dim3(256), 0, stream,
                     attnpk, wop, bo, y, (ushort*)nullptr);
}

// Round 12
// 246.719 us; speedup vs baseline: 1.1328x; 1.0122x over previous
//
#include <hip/hip_runtime.h>
#include <cstddef>

// Problem constants
// B=8, DIM=256, NH=8, H=W=56, G=4, CG=64, GH=2, HC=32, Hk=Wk=8, ns=64

typedef short bf16x8 __attribute__((ext_vector_type(8)));
typedef float f32x4 __attribute__((ext_vector_type(4)));
typedef _Float16 h2v __attribute__((ext_vector_type(2)));

static __device__ __forceinline__ ushort f2bf(float f) {
  union { float f; unsigned u; } v; v.f = f;
  unsigned r = v.u + 0x7fffu + ((v.u >> 16) & 1u);   // RNE
  return (ushort)(r >> 16);
}
static __device__ __forceinline__ float bf2f(ushort u) {
  union { unsigned u; float f; } v; v.u = ((unsigned)u) << 16;
  return v.f;
}

// ws float offsets
#define OFF_FEATB 0u          // feat bf16 [b*3136+m][256c] (later reused as attnpk)
#define OFF_QPK   3211264u    // q bf16 [b*3136+m][256c]
#define OFF_Q     6422528u    // q fp32 [b][c][m]
#define OFF_POS   12845056u   // 4096
#define OFF_XS    12849152u   // 131072 (offset-conv scratch)
#define OFF_KPK   12980224u   // K bf16 pack [b][h][c8=4][n=64][8]
#define OFF_VPK   13045760u   // V bf16 pack [b][h][n8=8][c=32][8]
#define OFF_PWP   13111296u   // pw pack 49152 bf16 = 24576 fl
#define OFF_WQP   13135872u   // 65536 bf16 = 32768 fl
#define OFF_WOP   13168640u   // 32768 fl
#define OFF_WKT   13201408u   // 65536 fl (fp32 wk^T)
#define OFF_WVT   13266944u   // 65536 fl -> end 13332480 fl (53.3 MB)

// ---------------------------------------------------------------------------
// Kernel P: pack weights. m=0 pwp, 1 wqp, 2 wop (bf16 frag packs [k8][o][8]);
// m=3 wkT, m=4 wvT (fp32 transposed [c][o]).
__global__ __launch_bounds__(256) void k_pack(
    const float* __restrict__ pw, const float* __restrict__ wq,
    const float* __restrict__ wk, const float* __restrict__ wv,
    const float* __restrict__ wo, ushort* __restrict__ pwp,
    ushort* __restrict__ wqp, ushort* __restrict__ wop,
    float* __restrict__ wkT, float* __restrict__ wvT) {
  const int o = blockIdx.x, t = threadIdx.x, m = blockIdx.y;
  if (m == 0) {
    if (t < 192) pwp[((t >> 3) * 256 + o) * 8 + (t & 7)] = f2bf(pw[o * 192 + t]);
  } else if (m == 1) {
    wqp[((t >> 3) * 256 + o) * 8 + (t & 7)] = f2bf(wq[o * 256 + t]);
  } else if (m == 2) {
    wop[((t >> 3) * 256 + o) * 8 + (t & 7)] = f2bf(wo[o * 256 + t]);
  } else if (m == 3) {
    wkT[t * 256 + o] = wk[o * 256 + t];
  } else {
    wvT[t * 256 + o] = wv[o * 256 + t];
  }
}

// ---------------------------------------------------------------------------
// Kernel A: patch conv (im2col MFMA, K=192) + bias + channel-LN -> bf16 [m][c]
// Block = 4 waves x 32 rows = 128 rows; B slices (16KB) LDS double-buffered.
// A-frags read fp32 x directly (2 float4 + cvt) -- no separate xcvt pass.
__global__ __launch_bounds__(256) void k_patch_mfma(
    const float* __restrict__ x, const ushort* __restrict__ pwp,
    const float* __restrict__ pb, const float* __restrict__ g1,
    const float* __restrict__ b1, ushort* __restrict__ featb) {
  __shared__ ushort Bs[2][8192];
  const int t = threadIdx.x;
  const int lane = t & 63, w = t >> 6;
  const int lr = lane & 15, kg = lane >> 4;
  const int m_base = blockIdx.x * 128 + w * 32;

  size_t abase[2];
#pragma unroll
  for (int mr = 0; mr < 2; mr++) {
    int mA = m_base + mr * 16 + lr;
    int bA = mA / 3136;
    int posA = mA - bA * 3136;
    int ohA = posA / 56;
    int owA = posA - ohA * 56;
    abase[mr] = (((size_t)bA * 3) * 448 + ohA * 8) * 448 + owA * 8;
  }

  f32x4 acc[2][16];
#pragma unroll
  for (int f = 0; f < 16; f++) {
    float bv = pb[f * 16 + lr];
    acc[0][f] = (f32x4){bv, bv, bv, bv};
    acc[1][f] = (f32x4){bv, bv, bv, bv};
  }

  bf16x8 st[4];
#pragma unroll
  for (int i = 0; i < 4; i++)
    st[i] = *(const bf16x8*)(pwp + i * 2048 + t * 8);
#pragma unroll
  for (int i = 0; i < 4; i++)
    *(bf16x8*)(&Bs[0][i * 2048 + t * 8]) = st[i];
  __syncthreads();
  int p = 0;
  for (int ks = 0; ks < 6; ks++) {
    if (ks < 5) {
#pragma unroll
      for (int i = 0; i < 4; i++)
        st[i] = *(const bf16x8*)(pwp + (ks + 1) * 8192 + i * 2048 + t * 8);
    }
    const int k8 = ks * 4 + kg;
    const int ci = k8 >> 3, ii = k8 & 7;
    bf16x8 a0, a1;
#pragma unroll
    for (int mr = 0; mr < 2; mr++) {
      const float* xp = x + abase[mr] + (size_t)ci * 200704 + ii * 448;
      float4 v0 = *(const float4*)xp;
      float4 v1 = *(const float4*)(xp + 4);
      bf16x8 a;
      a[0] = (short)f2bf(v0.x); a[1] = (short)f2bf(v0.y);
      a[2] = (short)f2bf(v0.z); a[3] = (short)f2bf(v0.w);
      a[4] = (short)f2bf(v1.x); a[5] = (short)f2bf(v1.y);
      a[6] = (short)f2bf(v1.z); a[7] = (short)f2bf(v1.w);
      if (mr == 0) a0 = a; else a1 = a;
    }
    const ushort* bsl = &Bs[p][kg * 2048];
#pragma unroll
    for (int f = 0; f < 16; f++) {
      bf16x8 bfr = *(const bf16x8*)(bsl + (f * 16 + lr) * 8);
      acc[0][f] = __builtin_amdgcn_mfma_f32_16x16x32_bf16(a0, bfr, acc[0][f], 0, 0, 0);
      acc[1][f] = __builtin_amdgcn_mfma_f32_16x16x32_bf16(a1, bfr, acc[1][f], 0, 0, 0);
    }
    __syncthreads();
    if (ks < 5) {
#pragma unroll
      for (int i = 0; i < 4; i++)
        *(bf16x8*)(&Bs[p ^ 1][i * 2048 + t * 8]) = st[i];
      __syncthreads();
      p ^= 1;
    }
  }

#pragma unroll
  for (int mr = 0; mr < 2; mr++) {
    float mean[4], rstd[4];
#pragma unroll
    for (int j = 0; j < 4; j++) {
      float s1 = 0.f, s2 = 0.f;
#pragma unroll
      for (int f = 0; f < 16; f++) { float v = acc[mr][f][j]; s1 += v; s2 += v * v; }
#pragma unroll
      for (int off = 8; off >= 1; off >>= 1) {
        s1 += __shfl_xor(s1, off);
        s2 += __shfl_xor(s2, off);
      }
      float mn = s1 * (1.f / 256.f);
      float var = s2 * (1.f / 256.f) - mn * mn;
      mean[j] = mn; rstd[j] = rsqrtf(var + 1e-5f);
    }
#pragma unroll
    for (int f = 0; f < 16; f++) {
      const int c = f * 16 + lr;
      const float gg = g1[c], bb = b1[c];
#pragma unroll
      for (int j = 0; j < 4; j++) {
        const int mo = m_base + mr * 16 + kg * 4 + j;
        float v = (acc[mr][f][j] - mean[j]) * rstd[j] * gg + bb;
        featb[(size_t)mo * 256 + c] = f2bf(v);
      }
    }
  }
}

// ---------------------------------------------------------------------------
// Kernel B: MFMA GEMM, 128 rows/block (4 waves x 32), B staged in LDS.
__global__ __launch_bounds__(256) void k_gemm_mfma(
    const ushort* __restrict__ apk, const ushort* __restrict__ wp,
    const float* __restrict__ bias, float* __restrict__ out,
    ushort* __restrict__ opk) {
  __shared__ float smem[16448];           // 65792 B: Bs (32KB) / sA 64x257 f32
  ushort* Bs = (ushort*)smem;
  float* sA = smem;
  const int t = threadIdx.x;
  const int lane = t & 63, w = t >> 6;
  const int lr = lane & 15, kg = lane >> 4;
  const int m_base = blockIdx.x * 128 + w * 32;

  f32x4 acc[2][16];
#pragma unroll
  for (int f = 0; f < 16; f++) {
    float bv = bias[f * 16 + lr];
    acc[0][f] = (f32x4){bv, bv, bv, bv};
    acc[1][f] = (f32x4){bv, bv, bv, bv};
  }
  const ushort* a0p = apk + (size_t)(m_base + lr) * 256;
  const ushort* a1p = a0p + 16 * 256;

  bf16x8 st[4];
#pragma unroll
  for (int i = 0; i < 4; i++) st[i] = *(const bf16x8*)(wp + i * 2048 + t * 8);
#pragma unroll
  for (int i = 0; i < 4; i++) *(bf16x8*)(Bs + i * 2048 + t * 8) = st[i];
  __syncthreads();
  int p = 0;
  for (int ks = 0; ks < 8; ks++) {
    if (ks < 7) {
#pragma unroll
      for (int i = 0; i < 4; i++)
        st[i] = *(const bf16x8*)(wp + (ks + 1) * 8192 + i * 2048 + t * 8);
    }
    bf16x8 a0 = *(const bf16x8*)(a0p + ks * 32 + kg * 8);
    bf16x8 a1 = *(const bf16x8*)(a1p + ks * 32 + kg * 8);
    const ushort* bsl = Bs + p * 8192 + kg * 2048;
#pragma unroll
    for (int f = 0; f < 16; f++) {
      bf16x8 bfr = *(const bf16x8*)(bsl + (f * 16 + lr) * 8);
      acc[0][f] = __builtin_amdgcn_mfma_f32_16x16x32_bf16(a0, bfr, acc[0][f], 0, 0, 0);
      acc[1][f] = __builtin_amdgcn_mfma_f32_16x16x32_bf16(a1, bfr, acc[1][f], 0, 0, 0);
    }
    __syncthreads();
    if (ks < 7) {
#pragma unroll
      for (int i = 0; i < 4; i++)
        *(bf16x8*)(Bs + (p ^ 1) * 8192 + i * 2048 + t * 8) = st[i];
      __syncthreads();
      p ^= 1;
    }
  }
  __syncthreads();                         // reclaim smem for epilogue

#pragma unroll
  for (int h = 0; h < 2; h++) {
    if ((w >> 1) == h) {
      const int loc0 = (w & 1) * 32;
#pragma unroll
      for (int mr = 0; mr < 2; mr++)
#pragma unroll
        for (int f = 0; f < 16; f++)
#pragma unroll
          for (int j = 0; j < 4; j++)
            sA[(loc0 + mr * 16 + kg * 4 + j) * 257 + f * 16 + lr] = acc[mr][f][j];
    }
    __syncthreads();
    const int R0 = blockIdx.x * 128 + h * 64;
    const int bh = R0 / 3136;
    const int pos0 = R0 % 3136;            // multiple of 64
    {
      const int c = t;
      float* op = out + ((size_t)bh * 256 + c) * 3136 + pos0;
#pragma unroll
      for (int i4 = 0; i4 < 16; i4++) {
        float4 v;
        v.x = sA[(i4 * 4 + 0) * 257 + c];
        v.y = sA[(i4 * 4 + 1) * 257 + c];
        v.z = sA[(i4 * 4 + 2) * 257 + c];
        v.w = sA[(i4 * 4 + 3) * 257 + c];
        *(float4*)(op + i4 * 4) = v;
      }
    }
    if (opk) {
      const int mm = t & 63, cs = t >> 6;
      const int c0 = cs * 64;
#pragma unroll
      for (int jj = 0; jj < 8; jj++) {
        bf16x8 v8;
#pragma unroll
        for (int e = 0; e < 8; e++)
          v8[e] = (short)f2bf(sA[mm * 257 + c0 + jj * 8 + e]);
        *(bf16x8*)(opk + (size_t)(R0 + mm) * 256 + c0 + jj * 8) = v8;
      }
    }
    __syncthreads();
  }
}

// ---------------------------------------------------------------------------
// Kernel C1: offset depthwise conv (28x28, stride 8, pad 14).
__global__ __launch_bounds__(128) void k_offset_conv(
    const float* __restrict__ q, const float* __restrict__ dww,
    float* __restrict__ convo) {
  const int bg = blockIdx.y;
  const int wv = threadIdx.x >> 6;
  const int lane = threadIdx.x & 63;
  const int ch = blockIdx.x * 2 + wv;
  const int b = bg >> 2, g = bg & 3;

  __shared__ float pl[2][7072];
  float* P = pl[wv];
  for (int idx = lane; idx < 7072; idx += 64) P[idx] = 0.f;

  const float* qb = q + ((size_t)b * 256 + g * 64 + ch) * 3136;
  if (lane < 56) {
    for (int r = 0; r < 56; r++) {
      int hr = r + 14;
      P[hr * 84 + (lane + 14) + (hr >> 3)] = qb[r * 56 + lane];
    }
  }
  const int oh = lane >> 3, ow = lane & 7;
  const int chs = __builtin_amdgcn_readfirstlane(ch);
  const float* wr = dww + (size_t)chs * 784;
  float acc = 0.f;
  const int r0 = oh * 8, c0 = ow * 8;
  for (int i = 0; i < 28; i++) {
    int hr = r0 + i;
    const float* prow = P + hr * 84 + c0 + (hr >> 3);
    const float* wrr = wr + i * 28;
#pragma unroll
    for (int j = 0; j < 28; j++)
      acc = fmaf(prow[j], wrr[j], acc);
  }
  convo[bg * 4096 + lane * 64 + ch] = acc;
}

// ---------------------------------------------------------------------------
// Kernel C2: LN(64) + GELU + pointwise(2x64) + tanh + reference points.
__global__ __launch_bounds__(256) void k_offset_post(
    const float* __restrict__ convo, const float* __restrict__ dwb,
    const float* __restrict__ lng, const float* __restrict__ lnb,
    const float* __restrict__ pww, float* __restrict__ pos_ws,
    float* __restrict__ out_pos, float* __restrict__ out_ref) {
  const int bg = blockIdx.y;
  const int wv = threadIdx.x >> 6;
  const int lane = threadIdx.x & 63;
  const int idx = blockIdx.x * 4 + wv;
  const int oh = idx >> 3, ow = idx & 7;

  float acc = convo[bg * 4096 + idx * 64 + lane] + dwb[lane];

  float s1 = acc, s2 = acc * acc;
#pragma unroll
  for (int off = 32; off >= 1; off >>= 1) {
    s1 += __shfl_xor(s1, off);
    s2 += __shfl_xor(s2, off);
  }
  float m = s1 * (1.f / 64.f);
  float var = s2 * (1.f / 64.f) - m * m;
  float val = (acc - m) * rsqrtf(var + 1e-5f) * lng[lane] + lnb[lane];
  val = 0.5f * val * (1.f + erff(val * 0.70710678118654752f));
  float p0 = pww[lane] * val, p1 = pww[64 + lane] * val;
#pragma unroll
  for (int off = 32; off >= 1; off >>= 1) {
    p0 += __shfl_xor(p0, off);
    p1 += __shfl_xor(p1, off);
  }
  if (lane == 0) {
    float offy = tanhf(p0) * (2.0f / 7.0f);
    float offx = tanhf(p1) * (2.0f / 7.0f);
    float ry = (0.5f + oh) * (2.0f / 7.0f) - 1.0f;
    float rx = (0.5f + ow) * (2.0f / 7.0f) - 1.0f;
    float py = offy + ry, px = offx + rx;
    int o = bg * 128 + idx * 2;
    pos_ws[o] = py;  pos_ws[o + 1] = px;
    out_pos[o] = py; out_pos[o + 1] = px;
    out_ref[o] = ry; out_ref[o + 1] = rx;
  }
}

// ---------------------------------------------------------------------------
// Kernel DE: fused bilinear sampling + k,v projections -> bf16 B-frag packs.
// Block (n0/4, b): 4 points per block for 4x weight L2 reuse. Wave g samples
// group g's 64 channels for all 4 points; then 256x256 GEMV x4.
__global__ __launch_bounds__(256) void k_sample_kv(
    const ushort* __restrict__ featb, const float* __restrict__ pos_ws,
    const float* __restrict__ wkT, const float* __restrict__ bk,
    const float* __restrict__ wvT, const float* __restrict__ bv,
    ushort* __restrict__ kpk, ushort* __restrict__ vpk) {
  const int b = blockIdx.y;   // 0..7
  const int n0 = blockIdx.x * 4;
  const int t = threadIdx.x;
  const int g = t >> 6, lane = t & 63;
  const int bg = b * 4 + g;

  __shared__ float sxs[256 * 4];          // [c][u]
  {
    const size_t mb = (size_t)b * 3136;
    const int cofs = g * 64 + lane;
    float av4[4];
#pragma unroll
    for (int u = 0; u < 4; u++) {
      const int n = n0 + u;
      float py = pos_ws[bg * 128 + n * 2];
      float px = pos_ws[bg * 128 + n * 2 + 1];
      float gx = (px + 1.f) * 27.5f;
      float gy = (py + 1.f) * 27.5f;
      float x0f = floorf(gx), y0f = floorf(gy);
      int x0 = (int)x0f, y0 = (int)y0f;
      float wx1 = gx - x0f, wx0 = 1.f - wx1;
      float wy1 = gy - y0f, wy0 = 1.f - wy1;
      float acc = 0.f;
      if (x0 >= 0 && x0 <= 55 && y0 >= 0 && y0 <= 55)
        acc = fmaf(bf2f(featb[(mb + y0 * 56 + x0) * 256 + cofs]), wx0 * wy0, acc);
      if (x0 + 1 >= 0 && x0 + 1 <= 55 && y0 >= 0 && y0 <= 55)
        acc = fmaf(bf2f(featb[(mb + y0 * 56 + x0 + 1) * 256 + cofs]), wx1 * wy0, acc);
      if (x0 >= 0 && x0 <= 55 && y0 + 1 >= 0 && y0 + 1 <= 55)
        acc = fmaf(bf2f(featb[(mb + (y0 + 1) * 56 + x0) * 256 + cofs]), wx0 * wy1, acc);
      if (x0 + 1 >= 0 && x0 + 1 <= 55 && y0 + 1 >= 0 && y0 + 1 <= 55)
        acc = fmaf(bf2f(featb[(mb + (y0 + 1) * 56 + x0 + 1) * 256 + cofs]), wx1 * wy1, acc);
      av4[u] = acc;
    }
    *(float4*)&sxs[(g * 64 + lane) * 4] =
        make_float4(av4[0], av4[1], av4[2], av4[3]);
  }
  __syncthreads();

  float ak[4], av[4];
#pragma unroll
  for (int u = 0; u < 4; u++) { ak[u] = bk[t]; av[u] = bv[t]; }
  for (int c = 0; c < 256; c++) {
    float wkv = wkT[c * 256 + t];
    float wvv = wvT[c * 256 + t];
    float4 xv = *(const float4*)&sxs[c * 4];
    ak[0] = fmaf(wkv, xv.x, ak[0]); av[0] = fmaf(wvv, xv.x, av[0]);
    ak[1] = fmaf(wkv, xv.y, ak[1]); av[1] = fmaf(wvv, xv.y, av[1]);
    ak[2] = fmaf(wkv, xv.z, ak[2]); av[2] = fmaf(wvv, xv.z, av[2]);
    ak[3] = fmaf(wkv, xv.w, ak[3]); av[3] = fmaf(wvv, xv.w, av[3]);
  }
  const int h = t >> 5, cc = t & 31;
  const size_t base = (size_t)(b * 8 + h) * 2048;
#pragma unroll
  for (int u = 0; u < 4; u++) {
    const int n = n0 + u;
    kpk[base + (size_t)((cc >> 3) * 64 + n) * 8 + (cc & 7)] = f2bf(ak[u]);
    vpk[base + (size_t)((n >> 3) * 32 + cc) * 8 + (n & 7)] = f2bf(av[u]);
  }
}

// ---------------------------------------------------------------------------
// Kernel F: MFMA attention. Block = (b, g, 64-query tile); 4 waves x 16 q.
// Bias MLP per-thread in C-fragment layout, packed f16 via clang vector ext
// (native v_pk_fma_f16 / v_pk_max_f16 -- r10's library-half2 regression was
// codegen, not numerics; f16 accuracy verified in r10). Pbuf stride 88.
__global__ __launch_bounds__(256) void k_attn_mfma(
    const ushort* __restrict__ qpk, const ushort* __restrict__ kpk,
    const ushort* __restrict__ vpk, const float* __restrict__ pos_ws,
    const float* __restrict__ w1, const float* __restrict__ b1,
    const float* __restrict__ w2, ushort* __restrict__ attnpk) {
  const int bg = blockIdx.y;           // b*4+g
  const int b = bg >> 2, g = bg & 3;
  const int m0 = blockIdx.x * 64;
  const int t = threadIdx.x;
  const int lane = t & 63, w = t >> 6;
  const int lr = lane & 15, kg = lane >> 4;

  __shared__ ushort Pbuf[4][16 * 88];  // per-wave P staging, stride 88
  __shared__ ushort outb[64 * 72];     // epilogue tile
  __shared__ float posl[128];
  __shared__ h2v rpeh[32][5];          // {w1y,w1x,b1,w2a,w2b} dup pairs

  if (t < 128) posl[t] = pos_ws[bg * 128 + t];
  if (t < 32) {
    _Float16 a0 = (_Float16)w1[t * 2];
    _Float16 a1 = (_Float16)w1[t * 2 + 1];
    _Float16 a2 = (_Float16)b1[t];
    _Float16 a3 = (_Float16)w2[t];
    _Float16 a4 = (_Float16)w2[32 + t];
    rpeh[t][0] = (h2v){a0, a0};
    rpeh[t][1] = (h2v){a1, a1};
    rpeh[t][2] = (h2v){a2, a2};
    rpeh[t][3] = (h2v){a3, a3};
    rpeh[t][4] = (h2v){a4, a4};
  }
  __syncthreads();

  // --- bias MLP (packed f16, C-layout: pair p = nf*4+j ->
  //     row kg*4+j (query m0+w*16+...), col nf*16+lr (point n)) ---
  float qgy[4], qgx[4];
#pragma unroll
  for (int j = 0; j < 4; j++) {
    int m = m0 + w * 16 + kg * 4 + j;
    int my = m / 56, mx = m % 56;
    qgy[j] = (float)my * (56.0f / 55.0f) * (2.0f / 55.0f) - 1.0f;
    qgx[j] = (float)mx * (56.0f / 55.0f) * (2.0f / 55.0f) - 1.0f;
  }
  float tyv[16], txv[16];
#pragma unroll
  for (int nf = 0; nf < 4; nf++) {
    int n = nf * 16 + lr;
    float py = posl[2 * n], px = posl[2 * n + 1];
#pragma unroll
    for (int j = 0; j < 4; j++) {
      float dy = (qgy[j] - py) * 4.f;
      float dx = (qgx[j] - px) * 4.f;
      tyv[nf * 4 + j] = copysignf(__log2f(fabsf(dy) + 1.f) * (1.f / 3.f), dy);
      txv[nf * 4 + j] = copysignf(__log2f(fabsf(dx) + 1.f) * (1.f / 3.f), dx);
    }
  }
  h2v ty2[8], tx2[8], bb02[8], bb12[8];
  const h2v zz = (h2v){(_Float16)0.f, (_Float16)0.f};
#pragma unroll
  for (int k = 0; k < 8; k++) {
    ty2[k] = (h2v){(_Float16)tyv[2 * k], (_Float16)tyv[2 * k + 1]};
    tx2[k] = (h2v){(_Float16)txv[2 * k], (_Float16)txv[2 * k + 1]};
    bb02[k] = zz; bb12[k] = zz;
  }
  for (int jj = 0; jj < 32; jj++) {
    h2v hy = rpeh[jj][0], hx = rpeh[jj][1], hb = rpeh[jj][2];
    h2v ha = rpeh[jj][3], hc = rpeh[jj][4];
#pragma unroll
    for (int k = 0; k < 8; k++) {
      h2v hv = hy * ty2[k] + (hx * tx2[k] + hb);   // contracts to v_pk_fma_f16
      hv = __builtin_elementwise_max(hv, zz);      // v_pk_max_f16
      bb02[k] = bb02[k] + ha * hv;
      bb12[k] = bb12[k] + hc * hv;
    }
  }
  float bb0[16], bb1[16];
#pragma unroll
  for (int k = 0; k < 8; k++) {
    bb0[2 * k]     = (float)bb02[k].x;
    bb0[2 * k + 1] = (float)bb02[k].y;
    bb1[2 * k]     = (float)bb12[k].x;
    bb1[2 * k + 1] = (float)bb12[k].y;
  }

  const int mrow = m0 + w * 16 + lr;
  const float scale = 0.17677669529663687f;   // 1/sqrt(32)
  ushort* pb = Pbuf[w];

  f32x4 oacc[2][2];
#pragma unroll
  for (int gh = 0; gh < 2; gh++)
#pragma unroll
    for (int cf = 0; cf < 2; cf++) oacc[gh][cf] = (f32x4){0.f, 0.f, 0.f, 0.f};

#pragma unroll
  for (int gh = 0; gh < 2; gh++) {
    bf16x8 a = *(const bf16x8*)(qpk +
        ((size_t)(b * 3136 + mrow) * 256 + g * 64 + gh * 32 + kg * 8));
    const ushort* kbase = kpk + (size_t)(b * 8 + g * 2 + gh) * 2048;
    f32x4 s[4];
#pragma unroll
    for (int nf = 0; nf < 4; nf++) {
      bf16x8 bfr = *(const bf16x8*)(kbase + (size_t)(kg * 64 + nf * 16 + lr) * 8);
      s[nf] = __builtin_amdgcn_mfma_f32_16x16x32_bf16(
          a, bfr, (f32x4){0.f, 0.f, 0.f, 0.f}, 0, 0, 0);
    }
#pragma unroll
    for (int nf = 0; nf < 4; nf++)
#pragma unroll
      for (int j = 0; j < 4; j++)
        s[nf][j] = fmaf(s[nf][j], scale,
                        gh ? bb1[nf * 4 + j] : bb0[nf * 4 + j]);
#pragma unroll
    for (int j = 0; j < 4; j++) {
      float m1 = fmaxf(fmaxf(s[0][j], s[1][j]), fmaxf(s[2][j], s[3][j]));
#pragma unroll
      for (int o = 8; o >= 1; o >>= 1) m1 = fmaxf(m1, __shfl_xor(m1, o));
      float ss = 0.f;
#pragma unroll
      for (int nf = 0; nf < 4; nf++) {
        float e = __expf(s[nf][j] - m1);
        s[nf][j] = e;
        ss += e;
      }
#pragma unroll
      for (int o = 8; o >= 1; o >>= 1) ss += __shfl_xor(ss, o);
      float inv = 1.f / ss;
#pragma unroll
      for (int nf = 0; nf < 4; nf++) s[nf][j] *= inv;
    }
#pragma unroll
    for (int nf = 0; nf < 4; nf++)
#pragma unroll
      for (int j = 0; j < 4; j++)
        pb[(kg * 4 + j) * 88 + nf * 16 + lr] = f2bf(s[nf][j]);
    const ushort* vbase = vpk + (size_t)(b * 8 + g * 2 + gh) * 2048;
#pragma unroll
    for (int ks = 0; ks < 2; ks++) {
      bf16x8 pa = *(const bf16x8*)(pb + lr * 88 + ks * 32 + kg * 8);
#pragma unroll
      for (int cf = 0; cf < 2; cf++) {
        bf16x8 vb = *(const bf16x8*)(vbase +
            (size_t)((ks * 4 + kg) * 32 + cf * 16 + lr) * 8);
        oacc[gh][cf] = __builtin_amdgcn_mfma_f32_16x16x32_bf16(
            pa, vb, oacc[gh][cf], 0, 0, 0);
      }
    }
  }

#pragma unroll
  for (int gh = 0; gh < 2; gh++)
#pragma unroll
    for (int cf = 0; cf < 2; cf++)
#pragma unroll
      for (int j = 0; j < 4; j++)
        outb[(w * 16 + kg * 4 + j) * 72 + gh * 32 + cf * 16 + lr] =
            f2bf(oacc[gh][cf][j]);
  __syncthreads();
#pragma unroll
  for (int r2 = 0; r2 < 2; r2++) {
    int row = (t >> 3) + r2 * 32;
    int chunk = t & 7;
    bf16x8 v8 = *(const bf16x8*)(outb + row * 72 + chunk * 8);
    *(bf16x8*)(attnpk +
               ((size_t)(b * 3136 + m0 + row) * 256 + g * 64 + chunk * 8)) = v8;
  }
}

// ---------------------------------------------------------------------------
extern "C" void kernel_launch(void* const* d_in, const int* in_sizes, int n_in,
                              void* d_out, int out_size, void* d_ws,
                              size_t ws_size, hipStream_t stream) {
  const float* x       = (const float*)d_in[0];
  const float* patch_w = (const float*)d_in[1];
  const float* patch_b = (const float*)d_in[2];
  const float* ln1_g   = (const float*)d_in[3];
  const float* ln1_b   = (const float*)d_in[4];
  const float* wq      = (const float*)d_in[5];
  const float* bq      = (const float*)d_in[6];
  const float* wk      = (const float*)d_in[7];
  const float* bk      = (const float*)d_in[8];
  const float* wv      = (const float*)d_in[9];
  const float* bv      = (const float*)d_in[10];
  const float* wo      = (const float*)d_in[11];
  const float* bo      = (const float*)d_in[12];
  const float* off_dw_w = (const float*)d_in[13];
  const float* off_dw_b = (const float*)d_in[14];
  const float* off_ln_g = (const float*)d_in[15];
  const float* off_ln_b = (const float*)d_in[16];
  const float* off_pw_w = (const float*)d_in[17];
  const float* rpe_w1  = (const float*)d_in[18];
  const float* rpe_b1  = (const float*)d_in[19];
  const float* rpe_w2  = (const float*)d_in[20];

  float* ws = (float*)d_ws;
  ushort* featb = (ushort*)(ws + OFF_FEATB);   // bf16 [m][c]
  ushort* attnpk = featb;                      // reuse (feat dead after sample)
  ushort* qpk = (ushort*)(ws + OFF_QPK);       // bf16 [m][c]
  float* q    = ws + OFF_Q;                    // fp32 [c][m]
  float* posw = ws + OFF_POS;
  float* convo = ws + OFF_XS;
  ushort* kpk = (ushort*)(ws + OFF_KPK);
  ushort* vpk = (ushort*)(ws + OFF_VPK);
  ushort* pwp = (ushort*)(ws + OFF_PWP);
  ushort* wqp = (ushort*)(ws + OFF_WQP);
  ushort* wop = (ushort*)(ws + OFF_WOP);
  float* wkT  = ws + OFF_WKT;
  float* wvT  = ws + OFF_WVT;

  float* y = (float*)d_out;
  float* out_pos = y + 6422528;
  float* out_ref = out_pos + 4096;

  // P: weight packs / transposes
  hipLaunchKernelGGL(k_pack, dim3(256, 5), dim3(256), 0, stream,
                     patch_w, wq, wk, wv, wo, pwp, wqp, wop, wkT, wvT);
  // A: patch embed conv (MFMA, staged B, fp32 x) + LN -> feat bf16 [m][c]
  hipLaunchKernelGGL(k_patch_mfma, dim3(196), dim3(256), 0, stream,
                     x, pwp, patch_b, ln1_g, ln1_b, featb);
  // B: q = wq @ feat + bq  -> fp32 [c][m] + bf16 pack [m][c]
  hipLaunchKernelGGL(k_gemm_mfma, dim3(196), dim3(256), 0, stream,
                     featb, wqp, bq, q, qpk);
  // C1: offset depthwise conv
  hipLaunchKernelGGL(k_offset_conv, dim3(32, 32), dim3(128), 0, stream,
                     q, off_dw_w, convo);
  // C2: offset post (LN + GELU + pointwise + tanh) -> pos
  hipLaunchKernelGGL(k_offset_post, dim3(16, 32), dim3(256), 0, stream,
                     convo, off_dw_b, off_ln_g, off_ln_b, off_pw_w,
                     posw, out_pos, out_ref);
  // DE: fused sampling + k,v projections (4 pts/block) -> bf16 B-frag packs
  hipLaunchKernelGGL(k_sample_kv, dim3(16, 8), dim3(256), 0, stream,
                     featb, posw, wkT, bk, wvT, bv, kpk, vpk);
  // F: MFMA attention -> bf16 pack [m][c]
  hipLaunchKernelGGL(k_attn_mfma, dim3(49, 32), dim3(256), 0, stream,
                     qpk, kpk, vpk, posw, rpe_w1, rpe_b1, rpe_w2, attnpk);
  // G: y = wo @ attn_out + bo  (fp32 [c][m] = d_out)
  hipLaunchKernelGGL(k_gemm_mfma, dim3(196), dim3(256), 0, stream,
                     attnpk, wop, bo, y, (ushort*)nullptr);
}